// Round 1
// baseline (569.493 us; speedup 1.0000x reference)
//
#include <hip/hip_runtime.h>
#include <cstdint>
#include <cstddef>

// ---------------------------------------------------------------------------
// TokenRoutedMLP on MI355X (gfx950)
//   x:[8192,2048] f32, expert_ids:[8192] i32, gate_up:[8,2048,2048] f32,
//   down:[8,1024,2048] f32  ->  out:[8192,2048] f32
// Plan: route tokens -> expert-major padded tiles; f16 MFMA GEMMs with fused
// silu; weights pre-transposed+converted to f16 in ws ([n][k] layout).
// ws usage ~120 MB.
// ---------------------------------------------------------------------------

typedef __attribute__((ext_vector_type(8))) _Float16 half8;
typedef __attribute__((ext_vector_type(4))) _Float16 half4;
typedef __attribute__((ext_vector_type(4))) float floatx4;

#define AS_G __attribute__((address_space(1)))
#define AS_L __attribute__((address_space(3)))

__device__ __forceinline__ void async_cp16(void* lds, const void* g) {
  __builtin_amdgcn_global_load_lds((const AS_G uint32_t*)g, (AS_L uint32_t*)lds,
                                   16, 0, 0);
}

static constexpr int TTOK = 8192;
static constexpr int DIMK = 2048;
static constexpr int EI = 1024;
static constexpr int NE = 8;
static constexpr int PADT = 9216;      // sum ceil(n_e/128)*128 <= 8192+8*127
static constexpr int MAXTILES = 80;    // actual <= 72
static constexpr int NTILE_LAUNCH = 72;

// ---------------------------------------------------------------- routing ---
__global__ __launch_bounds__(256) void k_route(const int* __restrict__ ids,
                                               int* __restrict__ perm,
                                               int* __restrict__ te,
                                               int* __restrict__ tr0,
                                               int* __restrict__ tnr) {
  __shared__ int cnt[NE];
  __shared__ int cur[NE];
  int tid = threadIdx.x;
  if (tid < NE) cnt[tid] = 0;
  __syncthreads();
  for (int t = tid; t < TTOK; t += 256) atomicAdd(&cnt[ids[t]], 1);
  __syncthreads();
  if (tid == 0) {
    int pr = 0, nt = 0;
    for (int e = 0; e < NE; e++) {
      int n = cnt[e];
      cur[e] = pr;
      for (int j = 0; j < n; j += 128) {
        te[nt] = e; tr0[nt] = pr + j; tnr[nt] = min(128, n - j); nt++;
      }
      pr += ((n + 127) >> 7) << 7;
    }
    for (; nt < MAXTILES; nt++) { te[nt] = 0; tr0[nt] = 0; tnr[nt] = 0; }
  }
  __syncthreads();
  for (int i = tid; i < PADT; i += 256) perm[i] = 0;  // padding -> token 0
  __syncthreads();
  for (int t = tid; t < TTOK; t += 256) {
    int p = atomicAdd(&cur[ids[t]], 1);
    perm[p] = t;
  }
}

// ----------------------------------------------- weight transpose+convert ---
// src: [NE][K][N] f32 row-major  ->  dst: [NE][N][K] f16
template <int K, int N>
__global__ __launch_bounds__(256) void k_transpose_cvt(
    const float* __restrict__ src, _Float16* __restrict__ dst) {
  __shared__ float tile[64][67];
  int e = blockIdx.z;
  int n0 = blockIdx.x * 64, k0 = blockIdx.y * 64;
  const float* s = src + (size_t)e * K * N;
  _Float16* d = dst + (size_t)e * N * K;
  int tid = threadIdx.x;
  int kk = tid >> 4;           // 0..15
  int nn = (tid & 15) * 4;
#pragma unroll
  for (int i = 0; i < 4; i++) {
    float4 v = *(const float4*)(s + (size_t)(k0 + kk + i * 16) * N + n0 + nn);
    tile[kk + i * 16][nn + 0] = v.x;
    tile[kk + i * 16][nn + 1] = v.y;
    tile[kk + i * 16][nn + 2] = v.z;
    tile[kk + i * 16][nn + 3] = v.w;
  }
  __syncthreads();
  int nr = tid >> 4;
  int k4 = (tid & 15) * 4;
#pragma unroll
  for (int i = 0; i < 4; i++) {
    int n = nr + i * 16;
    half4 o;
    o[0] = (_Float16)tile[k4 + 0][n];
    o[1] = (_Float16)tile[k4 + 1][n];
    o[2] = (_Float16)tile[k4 + 2][n];
    o[3] = (_Float16)tile[k4 + 3][n];
    *(half4*)(d + (size_t)(n0 + n) * K + k0 + k4) = o;
  }
}

// --------------------------------------------------------- layer 1 (g,u) ---
// per block: 128 tokens x (64 gate cols + 64 up cols), K=2048, BK=32
__global__ __launch_bounds__(256) void k_gateup(
    const float* __restrict__ x, const _Float16* __restrict__ wt1,
    const int* __restrict__ perm, const int* __restrict__ te,
    const int* __restrict__ tr0, const int* __restrict__ tnr,
    _Float16* __restrict__ hbuf) {
  int tile = blockIdx.y;
  int nr = tnr[tile];
  if (nr == 0) return;
  int e = te[tile], r0 = tr0[tile];
  int col = blockIdx.x * 64;  // over EI
  int tid = threadIdx.x;

  __shared__ __align__(16) _Float16 As[128 * 32];
  __shared__ __align__(16) _Float16 Bg[64 * 32];
  __shared__ __align__(16) _Float16 Bu[64 * 32];

  // A staging: thread covers row=tid>>1, k-halves [16h,16h+16)
  int arow = tid >> 1, ah = tid & 1;
  const float* aptr = x + (size_t)perm[r0 + arow] * DIMK + ah * 16;
  int asw = (arow >> 1) & 3;
  _Float16* aw0 = As + ((size_t)arow * 4 + ((2 * ah) ^ asw)) * 8;
  _Float16* aw1 = As + ((size_t)arow * 4 + ((2 * ah + 1) ^ asw)) * 8;

  // B staging via global_load_lds: LDS chunk index == tid (swizzle on src q)
  int bn = tid >> 2;
  int bq = (tid & 3) ^ ((tid >> 3) & 3);
  const _Float16* bgp =
      wt1 + (size_t)e * DIMK * DIMK + (size_t)(col + bn) * DIMK + bq * 8;
  const _Float16* bup = bgp + (size_t)EI * DIMK;
  _Float16* bgl = Bg + (size_t)tid * 8;
  _Float16* bul = Bu + (size_t)tid * 8;

  int wave = tid >> 6, lane = tid & 63;
  int wm = (wave & 1) * 64, wn = (wave >> 1) * 32;
  int lm = lane & 15, lq = lane >> 4;
  int aoff[4], boff[2];
#pragma unroll
  for (int i = 0; i < 4; i++) {
    int r = wm + i * 16 + lm;
    aoff[i] = (r * 4 + (lq ^ ((r >> 1) & 3))) * 8;
  }
#pragma unroll
  for (int j = 0; j < 2; j++) {
    int n = wn + j * 16 + lm;
    boff[j] = (n * 4 + (lq ^ ((n >> 1) & 3))) * 8;
  }

  floatx4 accg[4][2], accu[4][2];
#pragma unroll
  for (int i = 0; i < 4; i++)
#pragma unroll
    for (int j = 0; j < 2; j++) {
      accg[i][j] = (floatx4)0.0f;
      accu[i][j] = (floatx4)0.0f;
    }

  for (int k0 = 0; k0 < DIMK; k0 += 32) {
    async_cp16(bgl, bgp + k0);
    async_cp16(bul, bup + k0);
    float4 f0 = *(const float4*)(aptr + k0);
    float4 f1 = *(const float4*)(aptr + k0 + 4);
    float4 f2 = *(const float4*)(aptr + k0 + 8);
    float4 f3 = *(const float4*)(aptr + k0 + 12);
    half8 p0, p1;
    p0[0] = (_Float16)f0.x; p0[1] = (_Float16)f0.y;
    p0[2] = (_Float16)f0.z; p0[3] = (_Float16)f0.w;
    p0[4] = (_Float16)f1.x; p0[5] = (_Float16)f1.y;
    p0[6] = (_Float16)f1.z; p0[7] = (_Float16)f1.w;
    p1[0] = (_Float16)f2.x; p1[1] = (_Float16)f2.y;
    p1[2] = (_Float16)f2.z; p1[3] = (_Float16)f2.w;
    p1[4] = (_Float16)f3.x; p1[5] = (_Float16)f3.y;
    p1[6] = (_Float16)f3.z; p1[7] = (_Float16)f3.w;
    *(half8*)aw0 = p0;
    *(half8*)aw1 = p1;
    __syncthreads();

    half8 af[4], bgf[2], buf_[2];
#pragma unroll
    for (int i = 0; i < 4; i++) af[i] = *(const half8*)(As + aoff[i]);
#pragma unroll
    for (int j = 0; j < 2; j++) {
      bgf[j] = *(const half8*)(Bg + boff[j]);
      buf_[j] = *(const half8*)(Bu + boff[j]);
    }
#pragma unroll
    for (int i = 0; i < 4; i++)
#pragma unroll
      for (int j = 0; j < 2; j++) {
        accg[i][j] = __builtin_amdgcn_mfma_f32_16x16x32_f16(af[i], bgf[j],
                                                            accg[i][j], 0, 0, 0);
        accu[i][j] = __builtin_amdgcn_mfma_f32_16x16x32_f16(af[i], buf_[j],
                                                            accu[i][j], 0, 0, 0);
      }
    __syncthreads();
  }

  // epilogue: h = silu(g)*u, store f16 (all 128 rows; tile owns them)
#pragma unroll
  for (int i = 0; i < 4; i++) {
    int rbase = wm + i * 16 + lq * 4;
#pragma unroll
    for (int j = 0; j < 2; j++) {
      int c = col + wn + j * 16 + lm;
#pragma unroll
      for (int rr = 0; rr < 4; rr++) {
        float g = accg[i][j][rr];
        float u = accu[i][j][rr];
        float h = g / (1.0f + __expf(-g)) * u;
        hbuf[(size_t)(r0 + rbase + rr) * EI + c] = (_Float16)h;
      }
    }
  }
}

// ------------------------------------------------------------- layer 2 -----
// per block: 128 tokens x 128 out cols, K=1024, BK=32
__global__ __launch_bounds__(256) void k_down(
    const _Float16* __restrict__ hbuf, const _Float16* __restrict__ wt2,
    const int* __restrict__ perm, const int* __restrict__ te,
    const int* __restrict__ tr0, const int* __restrict__ tnr,
    float* __restrict__ out) {
  int tile = blockIdx.y;
  int nr = tnr[tile];
  if (nr == 0) return;
  int e = te[tile], r0 = tr0[tile];
  int col = blockIdx.x * 128;
  int tid = threadIdx.x;

  __shared__ __align__(16) _Float16 As[128 * 32];
  __shared__ __align__(16) _Float16 Bs[128 * 32];

  int an = tid >> 2;
  int aq = (tid & 3) ^ ((tid >> 3) & 3);
  const _Float16* ap0 = hbuf + (size_t)(r0 + an) * EI + aq * 8;
  const _Float16* ap1 = hbuf + (size_t)(r0 + 64 + an) * EI + aq * 8;
  _Float16* al0 = As + (size_t)tid * 8;
  _Float16* al1 = As + 2048 + (size_t)tid * 8;
  const _Float16* wte = wt2 + (size_t)e * DIMK * EI;
  const _Float16* bp0 = wte + (size_t)(col + an) * EI + aq * 8;
  const _Float16* bp1 = wte + (size_t)(col + 64 + an) * EI + aq * 8;
  _Float16* bl0 = Bs + (size_t)tid * 8;
  _Float16* bl1 = Bs + 2048 + (size_t)tid * 8;

  int wave = tid >> 6, lane = tid & 63;
  int wm = (wave & 1) * 64, wn = (wave >> 1) * 64;
  int lm = lane & 15, lq = lane >> 4;
  int aoff[4], boff[4];
#pragma unroll
  for (int i = 0; i < 4; i++) {
    int r = wm + i * 16 + lm;
    aoff[i] = (r * 4 + (lq ^ ((r >> 1) & 3))) * 8;
    int n = wn + i * 16 + lm;
    boff[i] = (n * 4 + (lq ^ ((n >> 1) & 3))) * 8;
  }

  floatx4 acc[4][4];
#pragma unroll
  for (int i = 0; i < 4; i++)
#pragma unroll
    for (int j = 0; j < 4; j++) acc[i][j] = (floatx4)0.0f;

  for (int k0 = 0; k0 < EI; k0 += 32) {
    async_cp16(al0, ap0 + k0);
    async_cp16(al1, ap1 + k0);
    async_cp16(bl0, bp0 + k0);
    async_cp16(bl1, bp1 + k0);
    __syncthreads();
    half8 af[4], bf[4];
#pragma unroll
    for (int i = 0; i < 4; i++) {
      af[i] = *(const half8*)(As + aoff[i]);
      bf[i] = *(const half8*)(Bs + boff[i]);
    }
#pragma unroll
    for (int i = 0; i < 4; i++)
#pragma unroll
      for (int j = 0; j < 4; j++)
        acc[i][j] =
            __builtin_amdgcn_mfma_f32_16x16x32_f16(af[i], bf[j], acc[i][j], 0, 0, 0);
    __syncthreads();
  }

  // epilogue: scatter fp32 rows via perm, mask padding rows
#pragma unroll
  for (int i = 0; i < 4; i++) {
    int rbase = wm + i * 16 + lq * 4;
#pragma unroll
    for (int rr = 0; rr < 4; rr++) {
      int r = rbase + rr;
      if (r < nr) {
        int tok = perm[r0 + r];
        float* orow = out + (size_t)tok * DIMK + col;
#pragma unroll
        for (int j = 0; j < 4; j++) orow[wn + j * 16 + lm] = acc[i][j][rr];
      }
    }
  }
}

// ---------------------------------------------------------------- launch ---
extern "C" void kernel_launch(void* const* d_in, const int* in_sizes, int n_in,
                              void* d_out, int out_size, void* d_ws,
                              size_t ws_size, hipStream_t stream) {
  const float* x = (const float*)d_in[0];
  const int* ids = (const int*)d_in[1];
  const float* gup = (const float*)d_in[2];
  const float* dwn = (const float*)d_in[3];
  float* out = (float*)d_out;
  char* ws = (char*)d_ws;

  int* perm = (int*)ws;                         // 9216 ints
  int* te = (int*)(ws + 36864);                 // 80 ints
  int* tr0 = (int*)(ws + 36864 + 512);
  int* tnr = (int*)(ws + 36864 + 1024);
  _Float16* wt1 = (_Float16*)(ws + 65536);                     // 67,108,864 B
  _Float16* wt2 = (_Float16*)(ws + 65536 + 67108864);          // 33,554,432 B
  _Float16* hbuf = (_Float16*)(ws + 65536 + 67108864 + 33554432);  // 18,874,368 B

  k_route<<<dim3(1), dim3(256), 0, stream>>>(ids, perm, te, tr0, tnr);
  k_transpose_cvt<2048, 2048>
      <<<dim3(32, 32, 8), dim3(256), 0, stream>>>(gup, wt1);
  k_transpose_cvt<1024, 2048>
      <<<dim3(32, 16, 8), dim3(256), 0, stream>>>(dwn, wt2);
  k_gateup<<<dim3(16, NTILE_LAUNCH), dim3(256), 0, stream>>>(
      x, wt1, perm, te, tr0, tnr, hbuf);
  k_down<<<dim3(16, NTILE_LAUNCH), dim3(256), 0, stream>>>(
      hbuf, wt2, perm, te, tr0, tnr, out);
}

// Round 2
// 520.264 us; speedup vs baseline: 1.0946x; 1.0946x over previous
//
#include <hip/hip_runtime.h>
#include <cstdint>
#include <cstddef>

// ---------------------------------------------------------------------------
// TokenRoutedMLP on MI355X (gfx950)
//   x:[8192,2048] f32, expert_ids:[8192] i32, gate_up:[8,2048,2048] f32,
//   down:[8,1024,2048] f32  ->  out:[8192,2048] f32
// R2: pre-gather x->f16 (xg) so k_gateup stages everything via
// global_load_lds (m97 structure); transpose writes 16B; wt2 transposed
// after gateup, aliased into wt1 space (peak ws ~118 MB).
// ---------------------------------------------------------------------------

typedef __attribute__((ext_vector_type(8))) _Float16 half8;
typedef __attribute__((ext_vector_type(4))) float floatx4;

#define AS_G __attribute__((address_space(1)))
#define AS_L __attribute__((address_space(3)))

__device__ __forceinline__ void async_cp16(void* lds, const void* g) {
  __builtin_amdgcn_global_load_lds((const AS_G uint32_t*)g, (AS_L uint32_t*)lds,
                                   16, 0, 0);
}

static constexpr int TTOK = 8192;
static constexpr int DIMK = 2048;
static constexpr int EI = 1024;
static constexpr int NE = 8;
static constexpr int PADT = 9216;      // sum ceil(n_e/128)*128 <= 8192+8*127
static constexpr int MAXTILES = 80;    // actual <= 72
static constexpr int NTILE_LAUNCH = 72;

// ---------------------------------------------------------------- routing ---
__global__ __launch_bounds__(256) void k_route(const int* __restrict__ ids,
                                               int* __restrict__ perm,
                                               int* __restrict__ te,
                                               int* __restrict__ tr0,
                                               int* __restrict__ tnr) {
  __shared__ int cnt[NE];
  __shared__ int cur[NE];
  int tid = threadIdx.x;
  if (tid < NE) cnt[tid] = 0;
  __syncthreads();
  for (int t = tid; t < TTOK; t += 256) atomicAdd(&cnt[ids[t]], 1);
  __syncthreads();
  if (tid == 0) {
    int pr = 0, nt = 0;
    for (int e = 0; e < NE; e++) {
      int n = cnt[e];
      cur[e] = pr;
      for (int j = 0; j < n; j += 128) {
        te[nt] = e; tr0[nt] = pr + j; tnr[nt] = min(128, n - j); nt++;
      }
      pr += ((n + 127) >> 7) << 7;
    }
    for (; nt < MAXTILES; nt++) { te[nt] = 0; tr0[nt] = 0; tnr[nt] = 0; }
  }
  __syncthreads();
  for (int i = tid; i < PADT; i += 256) perm[i] = 0;  // padding -> token 0
  __syncthreads();
  for (int t = tid; t < TTOK; t += 256) {
    int p = atomicAdd(&cur[ids[t]], 1);
    perm[p] = t;
  }
}

// -------------------------------------------------- gather x -> f16 rows ---
__global__ __launch_bounds__(256) void k_gather_cvt(
    const float* __restrict__ x, const int* __restrict__ perm,
    _Float16* __restrict__ xg) {
  int r = blockIdx.x;
  int tok = perm[r];
  int c = threadIdx.x * 8;
  const float* s = x + (size_t)tok * DIMK + c;
  float4 a = *(const float4*)s;
  float4 b = *(const float4*)(s + 4);
  half8 o;
  o[0] = (_Float16)a.x; o[1] = (_Float16)a.y;
  o[2] = (_Float16)a.z; o[3] = (_Float16)a.w;
  o[4] = (_Float16)b.x; o[5] = (_Float16)b.y;
  o[6] = (_Float16)b.z; o[7] = (_Float16)b.w;
  *(half8*)(xg + (size_t)r * DIMK + c) = o;
}

// ----------------------------------------------- weight transpose+convert ---
// src: [NE][K][N] f32 row-major  ->  dst: [NE][N][K] f16
template <int K, int N>
__global__ __launch_bounds__(256) void k_transpose_cvt(
    const float* __restrict__ src, _Float16* __restrict__ dst) {
  __shared__ float tile[64][67];
  int e = blockIdx.z;
  int n0 = blockIdx.x * 64, k0 = blockIdx.y * 64;
  const float* s = src + (size_t)e * K * N;
  _Float16* d = dst + (size_t)e * N * K;
  int tid = threadIdx.x;
  int kk = tid >> 4;           // 0..15
  int nn = (tid & 15) * 4;
#pragma unroll
  for (int i = 0; i < 4; i++) {
    float4 v = *(const float4*)(s + (size_t)(k0 + kk + i * 16) * N + n0 + nn);
    tile[kk + i * 16][nn + 0] = v.x;
    tile[kk + i * 16][nn + 1] = v.y;
    tile[kk + i * 16][nn + 2] = v.z;
    tile[kk + i * 16][nn + 3] = v.w;
  }
  __syncthreads();
  int nrow = tid >> 3;         // 0..31
  int k8 = (tid & 7) * 8;      // 0..56
#pragma unroll
  for (int i = 0; i < 2; i++) {
    int n = nrow + i * 32;
    half8 o;
#pragma unroll
    for (int j = 0; j < 8; j++) o[j] = (_Float16)tile[k8 + j][n];
    *(half8*)(d + (size_t)(n0 + n) * K + k0 + k8) = o;
  }
}

// --------------------------------------------------------- layer 1 (g,u) ---
// per block: 128 tokens x (64 gate cols + 64 up cols), K=2048, BK=32
__global__ __launch_bounds__(256) void k_gateup(
    const _Float16* __restrict__ xg, const _Float16* __restrict__ wt1,
    const int* __restrict__ te, const int* __restrict__ tr0,
    const int* __restrict__ tnr, _Float16* __restrict__ hbuf) {
  int tile = blockIdx.y;
  int nr = tnr[tile];
  if (nr == 0) return;
  int e = te[tile], r0 = tr0[tile];
  int col = blockIdx.x * 64;  // over EI
  int tid = threadIdx.x;

  __shared__ __align__(16) _Float16 As[128 * 32];
  __shared__ __align__(16) _Float16 Bg[64 * 32];
  __shared__ __align__(16) _Float16 Bu[64 * 32];

  // A staging via global_load_lds (2 chunks/thread)
  int an = tid >> 2;
  int aq = (tid & 3) ^ ((tid >> 3) & 3);
  const _Float16* ap0 = xg + (size_t)(r0 + an) * DIMK + aq * 8;
  const _Float16* ap1 = xg + (size_t)(r0 + 64 + an) * DIMK + aq * 8;
  _Float16* al0 = As + (size_t)tid * 8;
  _Float16* al1 = As + 2048 + (size_t)tid * 8;

  // B staging (1 chunk/thread each for gate, up)
  int bn = tid >> 2;
  int bq = (tid & 3) ^ ((tid >> 3) & 3);
  const _Float16* bgp =
      wt1 + (size_t)e * DIMK * DIMK + (size_t)(col + bn) * DIMK + bq * 8;
  const _Float16* bup = bgp + (size_t)EI * DIMK;
  _Float16* bgl = Bg + (size_t)tid * 8;
  _Float16* bul = Bu + (size_t)tid * 8;

  int wave = tid >> 6, lane = tid & 63;
  int wm = (wave & 1) * 64, wn = (wave >> 1) * 32;
  int lm = lane & 15, lq = lane >> 4;
  int aoff[4], boff[2];
#pragma unroll
  for (int i = 0; i < 4; i++) {
    int r = wm + i * 16 + lm;
    aoff[i] = (r * 4 + (lq ^ ((r >> 1) & 3))) * 8;
  }
#pragma unroll
  for (int j = 0; j < 2; j++) {
    int n = wn + j * 16 + lm;
    boff[j] = (n * 4 + (lq ^ ((n >> 1) & 3))) * 8;
  }

  floatx4 accg[4][2], accu[4][2];
#pragma unroll
  for (int i = 0; i < 4; i++)
#pragma unroll
    for (int j = 0; j < 2; j++) {
      accg[i][j] = (floatx4)0.0f;
      accu[i][j] = (floatx4)0.0f;
    }

  for (int k0 = 0; k0 < DIMK; k0 += 32) {
    async_cp16(al0, ap0 + k0);
    async_cp16(al1, ap1 + k0);
    async_cp16(bgl, bgp + k0);
    async_cp16(bul, bup + k0);
    __syncthreads();
    half8 af[4], bgf[2], buf_[2];
#pragma unroll
    for (int i = 0; i < 4; i++) af[i] = *(const half8*)(As + aoff[i]);
#pragma unroll
    for (int j = 0; j < 2; j++) {
      bgf[j] = *(const half8*)(Bg + boff[j]);
      buf_[j] = *(const half8*)(Bu + boff[j]);
    }
#pragma unroll
    for (int i = 0; i < 4; i++)
#pragma unroll
      for (int j = 0; j < 2; j++) {
        accg[i][j] = __builtin_amdgcn_mfma_f32_16x16x32_f16(af[i], bgf[j],
                                                            accg[i][j], 0, 0, 0);
        accu[i][j] = __builtin_amdgcn_mfma_f32_16x16x32_f16(af[i], buf_[j],
                                                            accu[i][j], 0, 0, 0);
      }
    __syncthreads();
  }

  // epilogue: h = silu(g)*u, store f16 (all 128 rows; tile owns them)
#pragma unroll
  for (int i = 0; i < 4; i++) {
    int rbase = wm + i * 16 + lq * 4;
#pragma unroll
    for (int j = 0; j < 2; j++) {
      int c = col + wn + j * 16 + lm;
#pragma unroll
      for (int rr = 0; rr < 4; rr++) {
        float g = accg[i][j][rr];
        float u = accu[i][j][rr];
        float h = g / (1.0f + __expf(-g)) * u;
        hbuf[(size_t)(r0 + rbase + rr) * EI + c] = (_Float16)h;
      }
    }
  }
}

// ------------------------------------------------------------- layer 2 -----
// per block: 128 tokens x 128 out cols, K=1024, BK=32
__global__ __launch_bounds__(256) void k_down(
    const _Float16* __restrict__ hbuf, const _Float16* __restrict__ wt2,
    const int* __restrict__ perm, const int* __restrict__ te,
    const int* __restrict__ tr0, const int* __restrict__ tnr,
    float* __restrict__ out) {
  int tile = blockIdx.y;
  int nr = tnr[tile];
  if (nr == 0) return;
  int e = te[tile], r0 = tr0[tile];
  int col = blockIdx.x * 128;
  int tid = threadIdx.x;

  __shared__ __align__(16) _Float16 As[128 * 32];
  __shared__ __align__(16) _Float16 Bs[128 * 32];

  int an = tid >> 2;
  int aq = (tid & 3) ^ ((tid >> 3) & 3);
  const _Float16* ap0 = hbuf + (size_t)(r0 + an) * EI + aq * 8;
  const _Float16* ap1 = hbuf + (size_t)(r0 + 64 + an) * EI + aq * 8;
  _Float16* al0 = As + (size_t)tid * 8;
  _Float16* al1 = As + 2048 + (size_t)tid * 8;
  const _Float16* wte = wt2 + (size_t)e * DIMK * EI;
  const _Float16* bp0 = wte + (size_t)(col + an) * EI + aq * 8;
  const _Float16* bp1 = wte + (size_t)(col + 64 + an) * EI + aq * 8;
  _Float16* bl0 = Bs + (size_t)tid * 8;
  _Float16* bl1 = Bs + 2048 + (size_t)tid * 8;

  int wave = tid >> 6, lane = tid & 63;
  int wm = (wave & 1) * 64, wn = (wave >> 1) * 64;
  int lm = lane & 15, lq = lane >> 4;
  int aoff[4], boff[4];
#pragma unroll
  for (int i = 0; i < 4; i++) {
    int r = wm + i * 16 + lm;
    aoff[i] = (r * 4 + (lq ^ ((r >> 1) & 3))) * 8;
    int n = wn + i * 16 + lm;
    boff[i] = (n * 4 + (lq ^ ((n >> 1) & 3))) * 8;
  }

  floatx4 acc[4][4];
#pragma unroll
  for (int i = 0; i < 4; i++)
#pragma unroll
    for (int j = 0; j < 4; j++) acc[i][j] = (floatx4)0.0f;

  for (int k0 = 0; k0 < EI; k0 += 32) {
    async_cp16(al0, ap0 + k0);
    async_cp16(al1, ap1 + k0);
    async_cp16(bl0, bp0 + k0);
    async_cp16(bl1, bp1 + k0);
    __syncthreads();
    half8 af[4], bf[4];
#pragma unroll
    for (int i = 0; i < 4; i++) {
      af[i] = *(const half8*)(As + aoff[i]);
      bf[i] = *(const half8*)(Bs + boff[i]);
    }
#pragma unroll
    for (int i = 0; i < 4; i++)
#pragma unroll
      for (int j = 0; j < 4; j++)
        acc[i][j] =
            __builtin_amdgcn_mfma_f32_16x16x32_f16(af[i], bf[j], acc[i][j], 0, 0, 0);
    __syncthreads();
  }

  // epilogue: scatter fp32 rows via perm, mask padding rows
#pragma unroll
  for (int i = 0; i < 4; i++) {
    int rbase = wm + i * 16 + lq * 4;
#pragma unroll
    for (int rr = 0; rr < 4; rr++) {
      int r = rbase + rr;
      if (r < nr) {
        int tok = perm[r0 + r];
        float* orow = out + (size_t)tok * DIMK + col;
#pragma unroll
        for (int j = 0; j < 4; j++) orow[wn + j * 16 + lm] = acc[i][j][rr];
      }
    }
  }
}

// ---------------------------------------------------------------- launch ---
extern "C" void kernel_launch(void* const* d_in, const int* in_sizes, int n_in,
                              void* d_out, int out_size, void* d_ws,
                              size_t ws_size, hipStream_t stream) {
  const float* x = (const float*)d_in[0];
  const int* ids = (const int*)d_in[1];
  const float* gup = (const float*)d_in[2];
  const float* dwn = (const float*)d_in[3];
  float* out = (float*)d_out;
  char* ws = (char*)d_ws;

  int* perm = (int*)ws;                         // 9216 ints
  int* te = (int*)(ws + 36864);                 // 80 ints
  int* tr0 = (int*)(ws + 36864 + 512);
  int* tnr = (int*)(ws + 36864 + 1024);
  // wt1: [8][2048][2048] f16 = 67,108,864 B  @ 65536
  _Float16* wt1 = (_Float16*)(ws + 65536);
  // hbuf: [9216][1024] f16 = 18,874,368 B    @ 65536 + 67108864
  _Float16* hbuf = (_Float16*)(ws + 65536 + 67108864);
  // xg: [9216][2048] f16 = 37,748,736 B      @ 65536 + 67108864 + 18874368
  _Float16* xg = (_Float16*)(ws + 65536 + 67108864 + 18874368);
  // wt2 aliases wt1's space (transposed AFTER k_gateup is done with wt1)
  _Float16* wt2 = wt1;
  // peak ws = 65536 + 67108864 + 18874368 + 37748736 = 123,797,504 B (~118 MB)

  k_route<<<dim3(1), dim3(256), 0, stream>>>(ids, perm, te, tr0, tnr);
  k_gather_cvt<<<dim3(PADT), dim3(256), 0, stream>>>(x, perm, xg);
  k_transpose_cvt<2048, 2048>
      <<<dim3(32, 32, 8), dim3(256), 0, stream>>>(gup, wt1);
  k_gateup<<<dim3(16, NTILE_LAUNCH), dim3(256), 0, stream>>>(
      xg, wt1, te, tr0, tnr, hbuf);
  k_transpose_cvt<1024, 2048>
      <<<dim3(32, 16, 8), dim3(256), 0, stream>>>(dwn, wt2);
  k_down<<<dim3(16, NTILE_LAUNCH), dim3(256), 0, stream>>>(
      hbuf, wt2, perm, te, tr0, tnr, out);
}

// Round 4
// 491.498 us; speedup vs baseline: 1.1587x; 1.0585x over previous
//
#include <hip/hip_runtime.h>
#include <cstdint>
#include <cstddef>

// ---------------------------------------------------------------------------
// TokenRoutedMLP on MI355X (gfx950)
// R4: fix R3's fault — perm tail [pr_total, PADT) was left poisoned, and
// k_prep's gather dereferenced it. Now zero-filled. R3 structure kept:
// multi-block scatter routing; gather fused with gate_up transpose; BK=64.
// ---------------------------------------------------------------------------

typedef __attribute__((ext_vector_type(8))) _Float16 half8;
typedef __attribute__((ext_vector_type(4))) float floatx4;

#define AS_G __attribute__((address_space(1)))
#define AS_L __attribute__((address_space(3)))

__device__ __forceinline__ void async_cp16(void* lds, const void* g) {
  __builtin_amdgcn_global_load_lds((const AS_G uint32_t*)g, (AS_L uint32_t*)lds,
                                   16, 0, 0);
}

static constexpr int TTOK = 8192;
static constexpr int DIMK = 2048;
static constexpr int EI = 1024;
static constexpr int NE = 8;
static constexpr int PADT = 9216;
static constexpr int MAXTILES = 80;
static constexpr int NTILE_LAUNCH = 72;

// ------------------------------------------------- routing: hist + tiles ---
__global__ __launch_bounds__(256) void k_route(const int* __restrict__ ids,
                                               int* __restrict__ perm,
                                               int* __restrict__ te,
                                               int* __restrict__ tr0,
                                               int* __restrict__ tnr,
                                               int* __restrict__ cur) {
  __shared__ int cnt[NE];
  __shared__ int sstart[NE];
  __shared__ int snpad[NE];
  __shared__ int stotal;
  int tid = threadIdx.x;
  if (tid < NE) cnt[tid] = 0;
  __syncthreads();
  for (int t = tid; t < TTOK; t += 256) atomicAdd(&cnt[ids[t]], 1);
  __syncthreads();
  if (tid == 0) {
    int pr = 0, nt = 0;
    for (int e = 0; e < NE; e++) {
      int n = cnt[e];
      sstart[e] = pr;
      cur[e] = pr;
      int padded = ((n + 127) >> 7) << 7;
      snpad[e] = padded - n;
      for (int j = 0; j < n; j += 128) {
        te[nt] = e; tr0[nt] = pr + j; tnr[nt] = min(128, n - j); nt++;
      }
      pr += padded;
    }
    stotal = pr;
    for (; nt < MAXTILES; nt++) { te[nt] = 0; tr0[nt] = 0; tnr[nt] = 0; }
  }
  __syncthreads();
  // fill the padding slots of perm (within each expert's range) with token 0
  for (int e = 0; e < NE; e++) {
    int base = sstart[e] + cnt[e];
    for (int i = tid; i < snpad[e]; i += 256) perm[base + i] = 0;
  }
  // fill the unused tail [stotal, PADT) too — k_prep's gather reads it
  for (int i = stotal + tid; i < PADT; i += 256) perm[i] = 0;
}

// -------------------------------------------- routing: parallel scatter ----
__global__ __launch_bounds__(256) void k_scatter(const int* __restrict__ ids,
                                                 int* __restrict__ cur,
                                                 int* __restrict__ perm) {
  __shared__ int bcnt[NE], bbase[NE], bloc[NE];
  int tid = threadIdx.x;
  int t = blockIdx.x * 256 + tid;
  if (tid < NE) { bcnt[tid] = 0; bloc[tid] = 0; }
  __syncthreads();
  int e = ids[t];
  atomicAdd(&bcnt[e], 1);
  __syncthreads();
  if (tid < NE && bcnt[tid] > 0) bbase[tid] = atomicAdd(&cur[tid], bcnt[tid]);
  __syncthreads();
  int off = atomicAdd(&bloc[e], 1);
  perm[bbase[e] + off] = t;
}

// ------------------------------------------- transpose tile (64x64) body ---
template <int K, int N>
__device__ __forceinline__ void transpose_tile(const float* __restrict__ src,
                                               _Float16* __restrict__ dst,
                                               float (*tile)[67], int e,
                                               int n0, int k0, int tid) {
  const float* s = src + (size_t)e * K * N;
  _Float16* d = dst + (size_t)e * N * K;
  int kk = tid >> 4;
  int nn = (tid & 15) * 4;
#pragma unroll
  for (int i = 0; i < 4; i++) {
    float4 v = *(const float4*)(s + (size_t)(k0 + kk + i * 16) * N + n0 + nn);
    tile[kk + i * 16][nn + 0] = v.x;
    tile[kk + i * 16][nn + 1] = v.y;
    tile[kk + i * 16][nn + 2] = v.z;
    tile[kk + i * 16][nn + 3] = v.w;
  }
  __syncthreads();
  int nrow = tid >> 3;
  int k8 = (tid & 7) * 8;
#pragma unroll
  for (int i = 0; i < 2; i++) {
    int n = nrow + i * 32;
    half8 o;
#pragma unroll
    for (int j = 0; j < 8; j++) o[j] = (_Float16)tile[k8 + j][n];
    *(half8*)(d + (size_t)(n0 + n) * K + k0 + k8) = o;
  }
}

// ------------------------- fused: gather x->f16  +  gate_up transpose ------
__global__ __launch_bounds__(256) void k_prep(const float* __restrict__ gup,
                                              _Float16* __restrict__ wt1,
                                              const float* __restrict__ x,
                                              const int* __restrict__ perm,
                                              _Float16* __restrict__ xg) {
  __shared__ float tile[64][67];
  int b = blockIdx.x;
  int tid = threadIdx.x;
  if (b < 8192) {
    int e = b >> 10;
    int r = b & 1023;
    transpose_tile<DIMK, DIMK>(gup, wt1, tile, e, (r & 31) * 64, (r >> 5) * 64,
                               tid);
  } else {
    int row = b - 8192;
    int tok = perm[row];
    int c = tid * 8;
    const float* s = x + (size_t)tok * DIMK + c;
    float4 a = *(const float4*)s;
    float4 bb = *(const float4*)(s + 4);
    half8 o;
    o[0] = (_Float16)a.x; o[1] = (_Float16)a.y;
    o[2] = (_Float16)a.z; o[3] = (_Float16)a.w;
    o[4] = (_Float16)bb.x; o[5] = (_Float16)bb.y;
    o[6] = (_Float16)bb.z; o[7] = (_Float16)bb.w;
    *(half8*)(xg + (size_t)row * DIMK + c) = o;
  }
}

// --------------------------------------------- down-proj transpose ---------
__global__ __launch_bounds__(256) void k_t2(const float* __restrict__ dwn,
                                            _Float16* __restrict__ wt2) {
  __shared__ float tile[64][67];
  transpose_tile<EI, DIMK>(dwn, wt2, tile, blockIdx.z, blockIdx.x * 64,
                           blockIdx.y * 64, threadIdx.x);
}

// --------------------------------------------------------- layer 1 (g,u) ---
// per block: 128 tokens x (64 gate + 64 up cols), K=2048, BK=64 (2 slabs)
__global__ __launch_bounds__(256) void k_gateup(
    const _Float16* __restrict__ xg, const _Float16* __restrict__ wt1,
    const int* __restrict__ te, const int* __restrict__ tr0,
    const int* __restrict__ tnr, _Float16* __restrict__ hbuf) {
  int tile = blockIdx.y;
  int nr = tnr[tile];
  if (nr == 0) return;
  int e = te[tile], r0 = tr0[tile];
  int col = blockIdx.x * 64;
  int tid = threadIdx.x;

  __shared__ __align__(16) _Float16 As[128 * 64];  // 2 slabs of [128][32]
  __shared__ __align__(16) _Float16 Bg[64 * 64];   // 2 slabs of [64][32]
  __shared__ __align__(16) _Float16 Bu[64 * 64];

  int an = tid >> 2;
  int aq = (tid & 3) ^ ((tid >> 3) & 3);
  const _Float16* ap0 = xg + (size_t)(r0 + an) * DIMK + aq * 8;
  const _Float16* ap1 = ap0 + (size_t)64 * DIMK;
  _Float16* al0 = As + (size_t)tid * 8;
  _Float16* al1 = As + 2048 + (size_t)tid * 8;
  const _Float16* bgp =
      wt1 + (size_t)e * DIMK * DIMK + (size_t)(col + an) * DIMK + aq * 8;
  const _Float16* bup = bgp + (size_t)EI * DIMK;
  _Float16* bgl = Bg + (size_t)tid * 8;
  _Float16* bul = Bu + (size_t)tid * 8;

  int wave = tid >> 6, lane = tid & 63;
  int wm = (wave & 1) * 64, wn = (wave >> 1) * 32;
  int lm = lane & 15, lq = lane >> 4;
  int aoff[4], boff[2];
#pragma unroll
  for (int i = 0; i < 4; i++) {
    int r = wm + i * 16 + lm;
    aoff[i] = (r * 4 + (lq ^ ((r >> 1) & 3))) * 8;
  }
#pragma unroll
  for (int j = 0; j < 2; j++) {
    int n = wn + j * 16 + lm;
    boff[j] = (n * 4 + (lq ^ ((n >> 1) & 3))) * 8;
  }

  floatx4 accg[4][2], accu[4][2];
#pragma unroll
  for (int i = 0; i < 4; i++)
#pragma unroll
    for (int j = 0; j < 2; j++) {
      accg[i][j] = (floatx4)0.0f;
      accu[i][j] = (floatx4)0.0f;
    }

  for (int k0 = 0; k0 < DIMK; k0 += 64) {
    async_cp16(al0, ap0 + k0);
    async_cp16(al1, ap1 + k0);
    async_cp16(bgl, bgp + k0);
    async_cp16(bul, bup + k0);
    async_cp16(al0 + 4096, ap0 + k0 + 32);
    async_cp16(al1 + 4096, ap1 + k0 + 32);
    async_cp16(bgl + 2048, bgp + k0 + 32);
    async_cp16(bul + 2048, bup + k0 + 32);
    __syncthreads();
#pragma unroll
    for (int s = 0; s < 2; s++) {
      const _Float16* Ab = As + s * 4096;
      const _Float16* Bgb = Bg + s * 2048;
      const _Float16* Bub = Bu + s * 2048;
      half8 af[4], bgf[2], buf_[2];
#pragma unroll
      for (int i = 0; i < 4; i++) af[i] = *(const half8*)(Ab + aoff[i]);
#pragma unroll
      for (int j = 0; j < 2; j++) {
        bgf[j] = *(const half8*)(Bgb + boff[j]);
        buf_[j] = *(const half8*)(Bub + boff[j]);
      }
#pragma unroll
      for (int i = 0; i < 4; i++)
#pragma unroll
        for (int j = 0; j < 2; j++) {
          accg[i][j] = __builtin_amdgcn_mfma_f32_16x16x32_f16(
              af[i], bgf[j], accg[i][j], 0, 0, 0);
          accu[i][j] = __builtin_amdgcn_mfma_f32_16x16x32_f16(
              af[i], buf_[j], accu[i][j], 0, 0, 0);
        }
    }
    __syncthreads();
  }

#pragma unroll
  for (int i = 0; i < 4; i++) {
    int rbase = wm + i * 16 + lq * 4;
#pragma unroll
    for (int j = 0; j < 2; j++) {
      int c = col + wn + j * 16 + lm;
#pragma unroll
      for (int rr = 0; rr < 4; rr++) {
        float g = accg[i][j][rr];
        float u = accu[i][j][rr];
        float h = g / (1.0f + __expf(-g)) * u;
        hbuf[(size_t)(r0 + rbase + rr) * EI + c] = (_Float16)h;
      }
    }
  }
}

// ------------------------------------------------------------- layer 2 -----
// per block: 128 tokens x 128 out cols, K=1024, BK=64 (2 slabs)
__global__ __launch_bounds__(256) void k_down(
    const _Float16* __restrict__ hbuf, const _Float16* __restrict__ wt2,
    const int* __restrict__ perm, const int* __restrict__ te,
    const int* __restrict__ tr0, const int* __restrict__ tnr,
    float* __restrict__ out) {
  int tile = blockIdx.y;
  int nr = tnr[tile];
  if (nr == 0) return;
  int e = te[tile], r0 = tr0[tile];
  int col = blockIdx.x * 128;
  int tid = threadIdx.x;

  __shared__ __align__(16) _Float16 As[128 * 64];  // 2 slabs of [128][32]
  __shared__ __align__(16) _Float16 Bs[128 * 64];

  int an = tid >> 2;
  int aq = (tid & 3) ^ ((tid >> 3) & 3);
  const _Float16* ap0 = hbuf + (size_t)(r0 + an) * EI + aq * 8;
  const _Float16* ap1 = ap0 + (size_t)64 * EI;
  _Float16* al0 = As + (size_t)tid * 8;
  _Float16* al1 = As + 2048 + (size_t)tid * 8;
  const _Float16* wte = wt2 + (size_t)e * DIMK * EI;
  const _Float16* bp0 = wte + (size_t)(col + an) * EI + aq * 8;
  const _Float16* bp1 = bp0 + (size_t)64 * EI;
  _Float16* bl0 = Bs + (size_t)tid * 8;
  _Float16* bl1 = Bs + 2048 + (size_t)tid * 8;

  int wave = tid >> 6, lane = tid & 63;
  int wm = (wave & 1) * 64, wn = (wave >> 1) * 64;
  int lm = lane & 15, lq = lane >> 4;
  int aoff[4], boff[4];
#pragma unroll
  for (int i = 0; i < 4; i++) {
    int r = wm + i * 16 + lm;
    aoff[i] = (r * 4 + (lq ^ ((r >> 1) & 3))) * 8;
    int n = wn + i * 16 + lm;
    boff[i] = (n * 4 + (lq ^ ((n >> 1) & 3))) * 8;
  }

  floatx4 acc[4][4];
#pragma unroll
  for (int i = 0; i < 4; i++)
#pragma unroll
    for (int j = 0; j < 4; j++) acc[i][j] = (floatx4)0.0f;

  for (int k0 = 0; k0 < EI; k0 += 64) {
    async_cp16(al0, ap0 + k0);
    async_cp16(al1, ap1 + k0);
    async_cp16(bl0, bp0 + k0);
    async_cp16(bl1, bp1 + k0);
    async_cp16(al0 + 4096, ap0 + k0 + 32);
    async_cp16(al1 + 4096, ap1 + k0 + 32);
    async_cp16(bl0 + 4096, bp0 + k0 + 32);
    async_cp16(bl1 + 4096, bp1 + k0 + 32);
    __syncthreads();
#pragma unroll
    for (int s = 0; s < 2; s++) {
      const _Float16* Ab = As + s * 4096;
      const _Float16* Bb = Bs + s * 4096;
      half8 af[4], bf[4];
#pragma unroll
      for (int i = 0; i < 4; i++) {
        af[i] = *(const half8*)(Ab + aoff[i]);
        bf[i] = *(const half8*)(Bb + boff[i]);
      }
#pragma unroll
      for (int i = 0; i < 4; i++)
#pragma unroll
        for (int j = 0; j < 4; j++)
          acc[i][j] = __builtin_amdgcn_mfma_f32_16x16x32_f16(af[i], bf[j],
                                                             acc[i][j], 0, 0, 0);
    }
    __syncthreads();
  }

#pragma unroll
  for (int i = 0; i < 4; i++) {
    int rbase = wm + i * 16 + lq * 4;
#pragma unroll
    for (int rr = 0; rr < 4; rr++) {
      int r = rbase + rr;
      if (r < nr) {
        int tok = perm[r0 + r];
        float* orow = out + (size_t)tok * DIMK + col;
#pragma unroll
        for (int j = 0; j < 4; j++) orow[wn + j * 16 + lm] = acc[i][j][rr];
      }
    }
  }
}

// ---------------------------------------------------------------- launch ---
extern "C" void kernel_launch(void* const* d_in, const int* in_sizes, int n_in,
                              void* d_out, int out_size, void* d_ws,
                              size_t ws_size, hipStream_t stream) {
  const float* x = (const float*)d_in[0];
  const int* ids = (const int*)d_in[1];
  const float* gup = (const float*)d_in[2];
  const float* dwn = (const float*)d_in[3];
  float* out = (float*)d_out;
  char* ws = (char*)d_ws;

  int* perm = (int*)ws;                          // 9216 ints
  int* te = (int*)(ws + 36864);
  int* tr0 = (int*)(ws + 36864 + 512);
  int* tnr = (int*)(ws + 36864 + 1024);
  int* cur = (int*)(ws + 36864 + 1536);          // 8 ints
  _Float16* wt1 = (_Float16*)(ws + 65536);                  // 67,108,864 B
  _Float16* hbuf = (_Float16*)(ws + 65536 + 67108864);      // 18,874,368 B
  _Float16* xg = (_Float16*)(ws + 65536 + 67108864 + 18874368);  // 37,748,736 B
  _Float16* wt2 = wt1;  // aliased; k_t2 runs after k_gateup is done with wt1
  // peak ws = 123,797,504 B

  k_route<<<dim3(1), dim3(256), 0, stream>>>(ids, perm, te, tr0, tnr, cur);
  k_scatter<<<dim3(32), dim3(256), 0, stream>>>(ids, cur, perm);
  k_prep<<<dim3(8192 + PADT), dim3(256), 0, stream>>>(gup, wt1, x, perm, xg);
  k_gateup<<<dim3(16, NTILE_LAUNCH), dim3(256), 0, stream>>>(
      xg, wt1, te, tr0, tnr, hbuf);
  k_t2<<<dim3(32, 16, 8), dim3(256), 0, stream>>>(dwn, wt2);
  k_down<<<dim3(16, NTILE_LAUNCH), dim3(256), 0, stream>>>(
      hbuf, wt2, perm, te, tr0, tnr, out);
}